// Round 8
// baseline (11733.790 us; speedup 1.0000x reference)
//
#include <hip/hip_runtime.h>
#include <hip/hip_bf16.h>

#define NN 50000
#define TT 48
#define FIN 11
#define MB2 ((NN + 127) / 128)

typedef __bf16 bf16_t;
typedef __bf16 v8bf __attribute__((ext_vector_type(8)));
typedef __bf16 v2bf __attribute__((ext_vector_type(2)));
typedef float v4f __attribute__((ext_vector_type(4)));

__device__ __forceinline__ float sigm_(float x) {
  return __builtin_amdgcn_rcpf(1.0f + __expf(-x));
}
__device__ __forceinline__ float tanh_(float x) {
  return 1.0f - 2.0f * __builtin_amdgcn_rcpf(1.0f + __expf(2.0f * x));
}

#define MFMA16(A, B, C) C = __builtin_amdgcn_mfma_f32_16x16x32_bf16(A, B, C, 0, 0, 0)

// ---------------- weight packing: 8-strip MFMA-fragment order ----------------
// (unchanged from round 7 — twin row-half waves share the same chunks)
// PZ[w8][kt9][nf2][zr2][lane64][8]   -> 147456 bf16
// PH[w8][kt9][nf2][lane64][8]        ->  73728 bf16
// PU[half2][w8][kt8][g2][nf2][ln][8] -> 262144 bf16
// Fragment value = W[c][k], c = w*32+nf*16+(lane&15), k = kt*32+(lane>>4)*8+e.
__global__ void pack_w(const float* __restrict__ bbWx, const float* __restrict__ bbWh,
                       const float* __restrict__ uWx, const float* __restrict__ spWx,
                       bf16_t* __restrict__ PZ, bf16_t* __restrict__ PH,
                       bf16_t* __restrict__ PU) {
  int i0 = blockIdx.x * blockDim.x + threadIdx.x;
  int stride = gridDim.x * blockDim.x;
  for (int idx = i0; idx < 147456; idx += stride) {
    int e = idx & 7, lane = (idx >> 3) & 63, ch = idx >> 9;
    int w = ch / 36, r36 = ch - w * 36, kt = r36 >> 2, nf = (r36 >> 1) & 1, zr = r36 & 1;
    int l15 = lane & 15, q = lane >> 4;
    int c = w * 32 + nf * 16 + l15;
    int k = kt * 32 + q * 8 + e;
    float v = 0.f;
    if (k < 256) v = bbWh[(zr * 256 + c) * 256 + k];
    else if (k < 256 + FIN) v = bbWx[(zr * 256 + c) * FIN + (k - 256)];
    PZ[idx] = (bf16_t)v;
  }
  for (int idx = i0; idx < 73728; idx += stride) {
    int e = idx & 7, lane = (idx >> 3) & 63, ch = idx >> 9;
    int w = ch / 18, r18 = ch - w * 18, kt = r18 >> 1, nf = r18 & 1;
    int l15 = lane & 15, q = lane >> 4;
    int c = w * 32 + nf * 16 + l15;
    int k = kt * 32 + q * 8 + e;
    float v = 0.f;
    if (k < 256) v = bbWh[(512 + c) * 256 + k];
    else if (k < 256 + FIN) v = bbWx[(512 + c) * FIN + (k - 256)];
    PH[idx] = (bf16_t)v;
  }
  for (int idx = i0; idx < 262144; idx += stride) {
    int e = idx & 7, lane = (idx >> 3) & 63, ch = idx >> 9;
    int half = ch >> 8, r256 = ch & 255;
    int w = r256 >> 5, r32 = r256 & 31, kt = r32 >> 2, g = (r32 >> 1) & 1, nf = r32 & 1;
    int l15 = lane & 15, q = lane >> 4;
    int j = w * 32 + nf * 16 + l15;
    int gate = g * 2;
    int k = kt * 32 + q * 8 + e;
    const float* W = half ? spWx : uWx;
    PU[idx] = (bf16_t)W[(gate * 256 + j) * 256 + k];
  }
}

// ---------------- fused persistent sequence kernel ----------------
// 128-row tile, 1024 threads = 16 waves: wave = (row-half wrow, col-strip wv).
// Twin waves (wv equal, wrow different) read the SAME weight chunks -> unique
// weight stream per XCD halves vs round 7 (the L2-miss/fetch-rate limiter).
// LDS 136KB -> 1 block/CU, 16 waves/CU = 4/SIMD (same hiding as round 7).
// Per-wave work shape identical to round 7 (acc[4][2], VGPR ~64-96).
__global__ __launch_bounds__(1024, 4) void fused_seq(
    const float* __restrict__ X,
    const bf16_t* __restrict__ PZ, const bf16_t* __restrict__ PH,
    const bf16_t* __restrict__ PU,
    const float* __restrict__ bbx, const float* __restrict__ bbh,
    const float* __restrict__ ubx, const float* __restrict__ ubh,
    const float* __restrict__ spbx, const float* __restrict__ spbh,
    const float* __restrict__ Wu, const float* __restrict__ buv,
    const float* __restrict__ Ws, const float* __restrict__ bsv,
    const float* __restrict__ Wp, const float* __restrict__ bpv,
    float* __restrict__ out) {
  __shared__ __align__(16) bf16_t Hm[128 * 256];  // 65536 B, swizzled H tile
  __shared__ __align__(16) bf16_t Ha[128 * 32];   // 8192 B, aug cols (X|pad)
  __shared__ __align__(16) bf16_t Rm[128 * 256];  // 65536 B, rH / hs tile
  char* const Hmb = (char*)Hm;
  char* const Hab = (char*)Ha;
  char* const Rmb = (char*)Rm;

  const int tid = threadIdx.x;
  const int lane = tid & 63, l15 = tid & 15, quad = (tid & 63) >> 4, wave = tid >> 6;
  const int wrow = (wave >> 3) * 64;   // row-half: 0 or 64
  const int wv = wave & 7;             // col-strip: 0..7 (32 cols each)
  const int rowBase = blockIdx.x * 128;
  const int srow = tid >> 3, sj = tid & 7, sm = rowBase + srow;

  const bf16_t* const pz0 = PZ + wv * 18432 + lane * 8;
  const bf16_t* const ph0 = PH + wv * 9216 + lane * 8;
  const bf16_t* const pu0 = PU + wv * 16384 + lane * 8;
  const bf16_t* const pu1 = PU + 131072 + wv * 16384 + lane * 8;

  // ---- init: H = 0, aug = [X_0 | 0] (all pads zeroed) ----
  {
    uint4 z4 = make_uint4(0u, 0u, 0u, 0u);
    for (int i = tid; i < 4096; i += 1024) ((uint4*)Hmb)[i] = z4;
    if (tid < 512) ((uint4*)Hab)[tid] = z4;
  }
  __syncthreads();
  if (sm < NN) {
    bf16_t* xr = (bf16_t*)(Hab + (srow << 6));
    const float* xp = X + (long)sm * FIN;
    xr[sj] = (bf16_t)xp[sj];
    if (sj + 8 < FIN) xr[sj + 8] = (bf16_t)xp[sj + 8];
  }
  __syncthreads();

#pragma unroll 1
  for (int t = 0; t < TT; ++t) {
    v2bf zpk[4][2][2];  // z gate, bf16-packed, lives through phase 2

    // ============ phase 1a: z-gemm (K=288) ============
    {
      v4f az[4][2] = {};
#pragma unroll
      for (int kt = 0; kt < 9; ++kt) {
        v8bf a[4];
#pragma unroll
        for (int mf = 0; mf < 4; ++mf) {
          const int row = wrow + mf * 16 + l15;
          if (kt < 8)
            a[mf] = *(const v8bf*)(Hmb + (row << 9) +
                                   ((kt * 64 + quad * 16) ^ ((l15 & 7) << 4)));
          else
            a[mf] = *(const v8bf*)(Hab + (row << 6) + quad * 16);
        }
        const bf16_t* p = pz0 + kt * 2048;
        v8bf bz[2];
#pragma unroll
        for (int nf = 0; nf < 2; ++nf) bz[nf] = *(const v8bf*)(p + nf * 1024);
#pragma unroll
        for (int mf = 0; mf < 4; ++mf)
#pragma unroll
          for (int nf = 0; nf < 2; ++nf) MFMA16(a[mf], bz[nf], az[mf][nf]);
      }
#pragma unroll
      for (int nf = 0; nf < 2; ++nf) {
        const int c = wv * 32 + nf * 16 + l15;
        const float bz_ = bbx[c] + bbh[c];
#pragma unroll
        for (int mf = 0; mf < 4; ++mf)
#pragma unroll
          for (int rg = 0; rg < 4; ++rg)
            zpk[mf][nf][rg >> 1][rg & 1] = (bf16_t)sigm_(az[mf][nf][rg] + bz_);
      }
    }

    // ============ phase 1b: r-gemm ============
    {
      v4f ar[4][2] = {};
#pragma unroll
      for (int kt = 0; kt < 9; ++kt) {
        v8bf a[4];
#pragma unroll
        for (int mf = 0; mf < 4; ++mf) {
          const int row = wrow + mf * 16 + l15;
          if (kt < 8)
            a[mf] = *(const v8bf*)(Hmb + (row << 9) +
                                   ((kt * 64 + quad * 16) ^ ((l15 & 7) << 4)));
          else
            a[mf] = *(const v8bf*)(Hab + (row << 6) + quad * 16);
        }
        const bf16_t* p = pz0 + kt * 2048 + 512;
        v8bf br[2];
#pragma unroll
        for (int nf = 0; nf < 2; ++nf) br[nf] = *(const v8bf*)(p + nf * 1024);
#pragma unroll
        for (int mf = 0; mf < 4; ++mf)
#pragma unroll
          for (int nf = 0; nf < 2; ++nf) MFMA16(a[mf], br[nf], ar[mf][nf]);
      }
      // epi: rH -> Rm
#pragma unroll
      for (int nf = 0; nf < 2; ++nf) {
        const int c = wv * 32 + nf * 16 + l15;
        const float br_ = bbx[256 + c] + bbh[256 + c];
#pragma unroll
        for (int mf = 0; mf < 4; ++mf)
#pragma unroll
          for (int rg = 0; rg < 4; ++rg) {
            const int m = wrow + mf * 16 + quad * 4 + rg;
            const int off = (m << 9) + ((c * 2) ^ ((m & 7) << 4));
            const float hp = (float)*(const bf16_t*)(Hmb + off);
            *(bf16_t*)(Rmb + off) = (bf16_t)(sigm_(ar[mf][nf][rg] + br_) * hp);
          }
      }
    }
    __syncthreads();  // BAR1: Rm (rH) ready

    // prefetch X_{t+1} (nontemporal: streaming, keep L2 for weights)
    float xv0 = 0.f, xv1 = 0.f;
    if (t + 1 < TT && sm < NN) {
      const float* xp = X + ((long)(t + 1) * NN + sm) * FIN;
      xv0 = __builtin_nontemporal_load(xp + sj);
      if (sj + 8 < FIN) xv1 = __builtin_nontemporal_load(xp + sj + 8);
    }

    // ============ phase 2: h_tilde gemm + blend ============
    {
      v4f ah[4][2] = {};
#pragma unroll
      for (int kt = 0; kt < 9; ++kt) {
        v8bf a[4];
#pragma unroll
        for (int mf = 0; mf < 4; ++mf) {
          const int row = wrow + mf * 16 + l15;
          if (kt < 8)
            a[mf] = *(const v8bf*)(Rmb + (row << 9) +
                                   ((kt * 64 + quad * 16) ^ ((l15 & 7) << 4)));
          else
            a[mf] = *(const v8bf*)(Hab + (row << 6) + quad * 16);
        }
        const bf16_t* p = ph0 + kt * 1024;
        v8bf bh[2];
#pragma unroll
        for (int nf = 0; nf < 2; ++nf) bh[nf] = *(const v8bf*)(p + nf * 512);
#pragma unroll
        for (int mf = 0; mf < 4; ++mf)
#pragma unroll
          for (int nf = 0; nf < 2; ++nf) MFMA16(a[mf], bh[nf], ah[mf][nf]);
      }
      // epi2: Hm = z*Hm + (1-z)*tanh(ah+b)
#pragma unroll
      for (int nf = 0; nf < 2; ++nf) {
        const int c = wv * 32 + nf * 16 + l15;
        const float bh_ = bbx[512 + c] + bbh[512 + c];
#pragma unroll
        for (int mf = 0; mf < 4; ++mf)
#pragma unroll
          for (int rg = 0; rg < 4; ++rg) {
            const int m = wrow + mf * 16 + quad * 4 + rg;
            const int off = (m << 9) + ((c * 2) ^ ((m & 7) << 4));
            const float htl = tanh_(ah[mf][nf][rg] + bh_);
            const float z = (float)zpk[mf][nf][rg >> 1][rg & 1];
            const float hp = (float)*(const bf16_t*)(Hmb + off);
            *(bf16_t*)(Hmb + off) = (bf16_t)(z * hp + (1.f - z) * htl);
          }
      }
    }
    __syncthreads();  // BAR2: Hm updated; Rm free

    // stage X_{t+1} into Ha (readers are next-t phases, behind later barriers)
    {
      bf16_t* xr = (bf16_t*)(Hab + (srow << 6));
      xr[sj] = (bf16_t)xv0;
      if (sj + 8 < FIN) xr[sj + 8] = (bf16_t)xv1;
    }

    // ============ phase 3: gru_u / gru_sp (H=None) + heads ============
#pragma unroll 1
    for (int half = 0; half < 2; ++half) {
      const bf16_t* puh = half ? pu1 : pu0;
      const float* gbx = half ? spbx : ubx;
      const float* gbh = half ? spbh : ubh;
      v2bf zz2[4][2][2];  // gate z kept in registers (same thread owns cell)
      // ---- z-gate pass ----
      {
        v4f au[4][2] = {};
#pragma unroll
        for (int kt = 0; kt < 8; ++kt) {
          v8bf a[4];
#pragma unroll
          for (int mf = 0; mf < 4; ++mf) {
            const int row = wrow + mf * 16 + l15;
            a[mf] = *(const v8bf*)(Hmb + (row << 9) +
                                   ((kt * 64 + quad * 16) ^ ((l15 & 7) << 4)));
          }
          const bf16_t* p = puh + kt * 2048;
          v8bf bu[2];
#pragma unroll
          for (int nf = 0; nf < 2; ++nf) bu[nf] = *(const v8bf*)(p + nf * 512);
#pragma unroll
          for (int mf = 0; mf < 4; ++mf)
#pragma unroll
            for (int nf = 0; nf < 2; ++nf) MFMA16(a[mf], bu[nf], au[mf][nf]);
        }
#pragma unroll
        for (int nf = 0; nf < 2; ++nf) {
          const int j = wv * 32 + nf * 16 + l15;
          const float b0 = gbx[j] + gbh[j];
#pragma unroll
          for (int mf = 0; mf < 4; ++mf)
#pragma unroll
            for (int rg = 0; rg < 4; ++rg)
              zz2[mf][nf][rg >> 1][rg & 1] = (bf16_t)sigm_(au[mf][nf][rg] + b0);
        }
      }
      // ---- h-gate pass: hs = (1-zz)*tanh -> Rm ----
      {
        v4f au[4][2] = {};
#pragma unroll
        for (int kt = 0; kt < 8; ++kt) {
          v8bf a[4];
#pragma unroll
          for (int mf = 0; mf < 4; ++mf) {
            const int row = wrow + mf * 16 + l15;
            a[mf] = *(const v8bf*)(Hmb + (row << 9) +
                                   ((kt * 64 + quad * 16) ^ ((l15 & 7) << 4)));
          }
          const bf16_t* p = puh + kt * 2048 + 1024;
          v8bf bu[2];
#pragma unroll
          for (int nf = 0; nf < 2; ++nf) bu[nf] = *(const v8bf*)(p + nf * 512);
#pragma unroll
          for (int mf = 0; mf < 4; ++mf)
#pragma unroll
            for (int nf = 0; nf < 2; ++nf) MFMA16(a[mf], bu[nf], au[mf][nf]);
        }
#pragma unroll
        for (int nf = 0; nf < 2; ++nf) {
          const int j = wv * 32 + nf * 16 + l15;
          const float b1 = gbx[512 + j] + gbh[512 + j];
#pragma unroll
          for (int mf = 0; mf < 4; ++mf)
#pragma unroll
            for (int rg = 0; rg < 4; ++rg) {
              const int r = wrow + mf * 16 + quad * 4 + rg;
              const float zz = (float)zz2[mf][nf][rg >> 1][rg & 1];
              const float ht = tanh_(au[mf][nf][rg] + b1);
              *(bf16_t*)(Rmb + (r << 9) + ((j * 2) ^ ((r & 7) << 4))) =
                  (bf16_t)((1.f - zz) * ht);
            }
        }
      }
      __syncthreads();  // hs tile ready
      if (half == 0) {
        if (tid < 384) {
          const int r = tid / 3, k = tid - r * 3, m = rowBase + r;
          if (m < NN) {
            float s = 0.f;
            for (int j = 0; j < 256; j += 8) {
              v8bf hv = *(const v8bf*)(Rmb + (r << 9) + ((j * 2) ^ ((r & 7) << 4)));
              const float* w = Wu + k * 256 + j;
#pragma unroll
              for (int jj = 0; jj < 8; ++jj) s += (float)hv[jj] * w[jj];
            }
            __builtin_nontemporal_store(s + buv[k],
                                        &out[(long)t * (NN * 3) + (long)m * 3 + k]);
          }
        }
      } else {
        if (tid < 256) {
          const int r = tid >> 1, which = tid & 1, m = rowBase + r;
          if (m < NN) {
            const float* W = which ? Wp : Ws;
            float s = 0.f;
            for (int j = 0; j < 256; j += 8) {
              v8bf hv = *(const v8bf*)(Rmb + (r << 9) + ((j * 2) ^ ((r & 7) << 4)));
#pragma unroll
              for (int jj = 0; jj < 8; ++jj) s += (float)hv[jj] * W[j + jj];
            }
            s += which ? bpv[0] : bsv[0];
            __builtin_nontemporal_store(
                s, &out[(long)TT * NN * 3 + (long)which * TT * NN + (long)t * NN + m]);
          }
        }
      }
      __syncthreads();  // head reads done before Rm is overwritten
    }
  }
}

extern "C" void kernel_launch(void* const* d_in, const int* in_sizes, int n_in,
                              void* d_out, int out_size, void* d_ws, size_t ws_size,
                              hipStream_t stream) {
  const float* X    = (const float*)d_in[0];
  // d_in[1] edge_index: unused (ChebConv K=1 ignores edges)
  const float* bbWx = (const float*)d_in[2];
  const float* bbbx = (const float*)d_in[3];
  const float* bbWh = (const float*)d_in[4];
  const float* bbbh = (const float*)d_in[5];
  const float* uWx  = (const float*)d_in[6];
  const float* ubx  = (const float*)d_in[7];
  const float* ubh  = (const float*)d_in[9];   // u_Wh (d_in[8]) dead: H=None
  const float* spWx = (const float*)d_in[10];
  const float* spbx = (const float*)d_in[11];
  const float* spbh = (const float*)d_in[13];  // sp_Wh (d_in[12]) dead
  const float* Wu   = (const float*)d_in[14];
  const float* buv  = (const float*)d_in[15];
  const float* Ws   = (const float*)d_in[16];
  const float* bsv  = (const float*)d_in[17];
  const float* Wp   = (const float*)d_in[18];
  const float* bpv  = (const float*)d_in[19];
  float* out = (float*)d_out;

  char* ws = (char*)d_ws;
  bf16_t* PZ = (bf16_t*)(ws);                  // 147456*2 = 294912
  bf16_t* PH = (bf16_t*)(ws + 294912);         //  73728*2 = 147456
  bf16_t* PU = (bf16_t*)(ws + 442368);         // 262144*2 = 524288
  if (ws_size < (size_t)966656) return;

  pack_w<<<dim3(192), dim3(256), 0, stream>>>(bbWx, bbWh, uWx, spWx, PZ, PH, PU);
  fused_seq<<<dim3(MB2), dim3(1024), 0, stream>>>(X, PZ, PH, PU, bbbx, bbbh,
                                                  ubx, ubh, spbx, spbh,
                                                  Wu, buv, Ws, bsv, Wp, bpv, out);
}